// Round 5
// baseline (263.380 us; speedup 1.0000x reference)
//
#include <hip/hip_runtime.h>

#define NB   32
#define NC   3
#define NH   512
#define NW   512
#define KS   25
#define HALF 12
#define TILE 64
#define HALO 88    // TILE + 2*HALF
#define NS   60

__device__ __forceinline__ float clip01(float v) { return fminf(fmaxf(v, 0.f), 1.f); }

struct PParams {
  int f1, f2, f3, f4;
  float intensity, cx, cy, rxi, ryi;
  float oy0, oy1, ox0, ox1;
  float log1ma, nrain;
  float thr_lo, thr_hi;
};

// ---- rain column lists: each streak covers exactly 2 columns ----
__global__ void rain_cols_kernel(const float* __restrict__ rain_u,
                                 const float* __restrict__ rain_n_u,
                                 int* __restrict__ nlist,
                                 unsigned* __restrict__ packed)
{
  int t = blockIdx.x * 256 + threadIdx.x;      // t in [0, 32*512)
  if (t >= NB * NW) return;
  int b = t >> 9, wcol = t & 511;
  float n = floorf(20.f + 41.f * rain_n_u[b]);
  float wf = (float)wcol;
  int cnt = 0;
  for (int s = 0; s < NS; ++s) {
    if ((float)s < n) {
      float xc = floorf(rain_u[(b * NS + s) * 3 + 0] * 512.f);
      if (wf >= xc - 1.f && wf <= xc) {
        float y0 = floorf(rain_u[(b * NS + s) * 3 + 1] * 256.f);
        float y1 = 256.f + floorf(rain_u[(b * NS + s) * 3 + 2] * 256.f);
        packed[t * NS + cnt] = (((unsigned)y0) << 16) | (unsigned)y1;
        ++cnt;
      }
    }
  }
  nlist[t] = cnt;
}

// ---- pointwise chain applied to an 8-row column strip ----
template<bool USE_LISTS>
__device__ __forceinline__ void chain_and_store(
    float acc[8], const PParams& P, int b, int gx, int gy0,
    const float* __restrict__ noise_plane, const float* __restrict__ rain_u,
    const int* __restrict__ nlist, const unsigned* __restrict__ packed,
    float* __restrict__ out_plane)
{
  const float fx = (float)gx;

  // 2. glare
  if (P.f1) {
    float dx = (fx - P.cx) * P.rxi;
    float dx2 = dx * dx;
    #pragma unroll
    for (int k = 0; k < 8; ++k) {
      float dy = ((float)(gy0 + k) - P.cy) * P.ryi;
      float g = __expf(-(dx2 + dy * dy));
      acc[k] = clip01(acc[k] + P.intensity * g);
    }
  }
  // 3. occlusion
  if (P.f2 && fx >= P.ox0 && fx < P.ox1) {
    #pragma unroll
    for (int k = 0; k < 8; ++k) {
      float fy = (float)(gy0 + k);
      if (fy >= P.oy0 && fy < P.oy1) acc[k] = 0.f;
    }
  }
  // 4. rain
  if (P.f3) {
    float cnt[8];
    #pragma unroll
    for (int k = 0; k < 8; ++k) cnt[k] = 0.f;
    if (USE_LISTS) {
      int base = b * NW + gx;
      int c = nlist[base];
      for (int j = 0; j < c; ++j) {
        unsigned p = packed[base * NS + j];
        float y0 = (float)(p >> 16), y1 = (float)(p & 0xffffu);
        #pragma unroll
        for (int k = 0; k < 8; ++k) {
          float fy = (float)(gy0 + k);
          cnt[k] += (fy >= y0 && fy < y1) ? 1.f : 0.f;
        }
      }
    } else {
      for (int s = 0; s < NS; ++s) {
        if ((float)s < P.nrain) {
          float xc = floorf(rain_u[(b * NS + s) * 3 + 0] * 512.f);
          if (fx >= xc - 1.f && fx <= xc) {
            float y0 = floorf(rain_u[(b * NS + s) * 3 + 1] * 256.f);
            float y1 = 256.f + floorf(rain_u[(b * NS + s) * 3 + 2] * 256.f);
            #pragma unroll
            for (int k = 0; k < 8; ++k) {
              float fy = (float)(gy0 + k);
              cnt[k] += (fy >= y0 && fy < y1) ? 1.f : 0.f;
            }
          }
        }
      }
    }
    #pragma unroll
    for (int k = 0; k < 8; ++k) {
      if (cnt[k] != 0.f) {
        float d = exp2f(cnt[k] * P.log1ma);
        acc[k] = clip01(acc[k] * d + (1.f - d));
      }
    }
  }
  // 5. salt & pepper (read noise only when gated on)
  if (P.f4) {
    const float* np = noise_plane + (size_t)gy0 * NW + gx;
    #pragma unroll
    for (int k = 0; k < 8; ++k) {
      float nv = np[(size_t)k * NW];
      acc[k] = (nv < P.thr_lo) ? 0.f : ((nv > P.thr_hi) ? 1.f : acc[k]);
    }
  }
  float* op = out_plane + (size_t)gy0 * NW + gx;
  #pragma unroll
  for (int k = 0; k < 8; ++k) op[(size_t)k * NW] = acc[k];
}

// One tile per block (r3 structure — best so far). Stage-1 rewritten:
// tile-uniform edge/interior split + explicit 2-deep load pipeline so each
// wave keeps ~14 float4 loads in flight instead of 7 serialized ones.
template<bool USE_LISTS>
__global__ __launch_bounds__(256, 4)
void fused_kernel(const float* __restrict__ x, const float* __restrict__ sigma_u,
                  const float* __restrict__ glare_u, const float* __restrict__ occ_u,
                  const float* __restrict__ rain_u, const float* __restrict__ rain_n_u,
                  const float* __restrict__ rain_alpha_u, const float* __restrict__ noise_u,
                  const float* __restrict__ noise_amt_u, const int* __restrict__ flags,
                  const int* __restrict__ nlist, const unsigned* __restrict__ packed,
                  float* __restrict__ out)
{
  const int b = blockIdx.z, ch = blockIdx.y;
  const int ty0 = (blockIdx.x >> 3) * TILE, tx0 = (blockIdx.x & 7) * TILE;
  const int tid = threadIdx.x;

  const int f0 = flags[b * 5 + 0] > 0;
  PParams P;
  P.f1 = flags[b * 5 + 1] > 0;
  P.f2 = flags[b * 5 + 2] > 0;
  P.f3 = flags[b * 5 + 3] > 0;
  P.f4 = flags[b * 5 + 4] > 0;
  {
    float g0 = glare_u[b * 5 + 0], g1 = glare_u[b * 5 + 1], g2 = glare_u[b * 5 + 2],
          g3 = glare_u[b * 5 + 3], g4 = glare_u[b * 5 + 4];
    P.intensity = 0.4f + 0.5f * g0;
    P.rxi = 1.f / ((0.1f + 0.25f * g1) * 256.f);   // W/2
    P.ryi = 1.f / ((0.1f + 0.25f * g2) * 256.f);   // H/2
    P.cx = (0.2f + 0.6f * g3) * 512.f;
    P.cy = (0.2f + 0.6f * g4) * 512.f;
    float o0 = occ_u[b * 4 + 0], o1 = occ_u[b * 4 + 1],
          o2 = occ_u[b * 4 + 2], o3 = occ_u[b * 4 + 3];
    float ph = floorf(512.f * (0.1f + 0.3f * o0));
    float pw = floorf(512.f * (0.1f + 0.3f * o1));
    P.oy0 = floorf(o2 * (512.f - ph)); P.oy1 = P.oy0 + ph;
    P.ox0 = floorf(o3 * (512.f - pw)); P.ox1 = P.ox0 + pw;
    P.log1ma = log2f(1.f - (0.15f + 0.35f * rain_alpha_u[b]));
    P.nrain = floorf(20.f + 41.f * rain_n_u[b]);
    float half_amt = 0.5f * (0.01f + 0.07f * noise_amt_u[b]);
    P.thr_lo = half_amt; P.thr_hi = 1.f - half_amt;
  }

  const size_t plane = ((size_t)(b * NC + ch)) * (size_t)(NH * NW);
  const float* xp = x + plane;
  const float* np = noise_u + plane;
  float* op = out + plane;

  __shared__ __align__(16) float s_hb[HALO * TILE];   // 22.5 KB

  if (f0) {
    // ---- blur weights in registers ----
    float sig = 1.f + 3.f * sigma_u[b];
    float ninv2s2 = -1.f / (2.f * sig * sig);
    float wr[KS]; float s = 0.f;
    #pragma unroll
    for (int t = 0; t < KS; ++t) {
      float d = (float)t - 12.f;
      wr[t] = expf(d * d * ninv2s2);
      s += wr[t];
    }
    float inv = 1.f / s;
    #pragma unroll
    for (int t = 0; t < KS; ++t) wr[t] *= inv;

    // ---- stage 1: horizontal blur from global ----
    // mapping: thread = (row-group g, col-quad q); rows g, g+16, ..., 6 rows
    // for g<8, 5 rows for g>=8 (covers 88 halo rows). Wave-uniform trips.
    const int q = tid & 15, g = tid >> 4;
    const int gx0 = tx0 + q * 4;
    const int nrows = (g < 8) ? 6 : 5;

    if (tx0 != 0 && tx0 != 448) {
      // ======== interior tile: branch-free, 2-deep pipelined float4 loads ====
      const float* cb = xp + (gx0 - HALF);
      float4 A[7], B[7];

      #define LOADROW(DST, K)                                                  \
        {                                                                      \
          int gy_ = ty0 + g + 16 * (K) - HALF;                                 \
          if ((unsigned)gy_ < (unsigned)NH) {                                  \
            const float* p_ = cb + (size_t)gy_ * NW;                           \
            _Pragma("unroll")                                                  \
            for (int j = 0; j < 7; ++j)                                        \
              DST[j] = *reinterpret_cast<const float4*>(p_ + 4 * j);           \
          } else {                                                             \
            _Pragma("unroll")                                                  \
            for (int j = 0; j < 7; ++j)                                        \
              DST[j] = make_float4(0.f, 0.f, 0.f, 0.f);                        \
          }                                                                    \
        }

      #define COMPUTEROW(SRC, K)                                               \
        {                                                                      \
          float win_[28];                                                      \
          _Pragma("unroll")                                                    \
          for (int j = 0; j < 7; ++j) {                                        \
            win_[4 * j + 0] = SRC[j].x; win_[4 * j + 1] = SRC[j].y;            \
            win_[4 * j + 2] = SRC[j].z; win_[4 * j + 3] = SRC[j].w;            \
          }                                                                    \
          float a0 = 0.f, a1 = 0.f, a2 = 0.f, a3 = 0.f;                        \
          _Pragma("unroll")                                                    \
          for (int t = 0; t < KS; ++t) {                                       \
            float wt = wr[t];                                                  \
            a0 = fmaf(wt, win_[t + 0], a0);                                    \
            a1 = fmaf(wt, win_[t + 1], a1);                                    \
            a2 = fmaf(wt, win_[t + 2], a2);                                    \
            a3 = fmaf(wt, win_[t + 3], a3);                                    \
          }                                                                    \
          *reinterpret_cast<float4*>(&s_hb[(g + 16 * (K)) * TILE + q * 4]) =   \
              make_float4(a0, a1, a2, a3);                                     \
        }

      LOADROW(A, 0)
      LOADROW(B, 1)
      COMPUTEROW(A, 0) LOADROW(A, 2)
      COMPUTEROW(B, 1) LOADROW(B, 3)
      COMPUTEROW(A, 2) LOADROW(A, 4)
      COMPUTEROW(B, 3) if (nrows == 6) LOADROW(B, 5)
      COMPUTEROW(A, 4)
      if (nrows == 6) COMPUTEROW(B, 5)

      #undef LOADROW
      #undef COMPUTEROW
    } else {
      // ======== x-edge tile (tx0 == 0 or 448): guarded scalar loads ========
      for (int k = 0; k < nrows; ++k) {
        int r = g + 16 * k;
        int gy = ty0 + r - HALF;
        float a0 = 0.f, a1 = 0.f, a2 = 0.f, a3 = 0.f;
        if ((unsigned)gy < (unsigned)NH) {
          const float* rowp = xp + (size_t)gy * NW;
          float win[28];
          #pragma unroll
          for (int j = 0; j < 28; ++j) {
            int gx = gx0 - HALF + j;
            win[j] = ((unsigned)gx < (unsigned)NW) ? rowp[gx] : 0.f;
          }
          #pragma unroll
          for (int t = 0; t < KS; ++t) {
            float wt = wr[t];
            a0 = fmaf(wt, win[t + 0], a0);
            a1 = fmaf(wt, win[t + 1], a1);
            a2 = fmaf(wt, win[t + 2], a2);
            a3 = fmaf(wt, win[t + 3], a3);
          }
        }
        *reinterpret_cast<float4*>(&s_hb[r * TILE + q * 4]) =
            make_float4(a0, a1, a2, a3);
      }
    }
    __syncthreads();

    // ---- stage 2: vertical blur on 8-row strips + fused pointwise chain ----
    for (int i = tid; i < 512; i += 256) {
      int xq = i & 63, sy = i >> 6;
      int gx = tx0 + xq, gy0 = ty0 + sy * 8;
      float wincol[32];
      #pragma unroll
      for (int j = 0; j < 32; ++j) wincol[j] = s_hb[(sy * 8 + j) * TILE + xq];
      float acc[8];
      #pragma unroll
      for (int k = 0; k < 8; ++k) {
        float a = 0.f;
        #pragma unroll
        for (int t = 0; t < KS; ++t) a = fmaf(wr[t], wincol[k + t], a);
        acc[k] = clip01(a);
      }
      chain_and_store<USE_LISTS>(acc, P, b, gx, gy0, np, rain_u, nlist, packed, op);
    }
  } else {
    // ---- no blur: pure streaming path (no LDS, no sync) ----
    for (int i = tid; i < 512; i += 256) {
      int xq = i & 63, sy = i >> 6;
      int gx = tx0 + xq, gy0 = ty0 + sy * 8;
      float acc[8];
      #pragma unroll
      for (int k = 0; k < 8; ++k) acc[k] = xp[(size_t)(gy0 + k) * NW + gx];
      chain_and_store<USE_LISTS>(acc, P, b, gx, gy0, np, rain_u, nlist, packed, op);
    }
  }
}

extern "C" void kernel_launch(void* const* d_in, const int* in_sizes, int n_in,
                              void* d_out, int out_size, void* d_ws, size_t ws_size,
                              hipStream_t stream)
{
  const float* x            = (const float*)d_in[0];
  const float* sigma_u      = (const float*)d_in[1];
  const float* glare_u      = (const float*)d_in[2];
  const float* occ_u        = (const float*)d_in[3];
  const float* rain_u       = (const float*)d_in[4];
  const float* rain_n_u     = (const float*)d_in[5];
  const float* rain_alpha_u = (const float*)d_in[6];
  const float* noise_u      = (const float*)d_in[7];
  const float* noise_amt_u  = (const float*)d_in[8];
  const int*   flags        = (const int*)d_in[9];
  float* out = (float*)d_out;

  const size_t nlist_bytes  = (size_t)NB * NW * sizeof(int);
  const size_t packed_bytes = (size_t)NB * NW * NS * sizeof(unsigned);
  const bool use_lists = ws_size >= nlist_bytes + packed_bytes;

  int* nlist = (int*)d_ws;
  unsigned* packed = (unsigned*)((char*)d_ws + nlist_bytes);

  dim3 grid(64, NC, NB);   // 8x8 tiles, 3 channels, 32 samples
  if (use_lists) {
    rain_cols_kernel<<<(NB * NW + 255) / 256, 256, 0, stream>>>(rain_u, rain_n_u, nlist, packed);
    fused_kernel<true><<<grid, 256, 0, stream>>>(
        x, sigma_u, glare_u, occ_u, rain_u, rain_n_u, rain_alpha_u,
        noise_u, noise_amt_u, flags, nlist, packed, out);
  } else {
    fused_kernel<false><<<grid, 256, 0, stream>>>(
        x, sigma_u, glare_u, occ_u, rain_u, rain_n_u, rain_alpha_u,
        noise_u, noise_amt_u, flags, (const int*)nullptr, (const unsigned*)nullptr, out);
  }
}

// Round 6
// 165.240 us; speedup vs baseline: 1.5939x; 1.5939x over previous
//
#include <hip/hip_runtime.h>

#define NB   32
#define NC   3
#define NH   512
#define NW   512
#define KS   25
#define HALF 12
#define TILE 64
#define HALO 88    // TILE + 2*HALF
#define NS   60

__device__ __forceinline__ float clip01(float v) { return fminf(fmaxf(v, 0.f), 1.f); }

struct PParams {
  int f1, f2, f3, f4;
  float intensity, cx, cy, rxi, ryi;
  float oy0, oy1, ox0, ox1;
  float log1ma, nrain;
  float thr_lo, thr_hi;
};

// ---- rain column lists: each streak covers exactly 2 columns ----
__global__ void rain_cols_kernel(const float* __restrict__ rain_u,
                                 const float* __restrict__ rain_n_u,
                                 int* __restrict__ nlist,
                                 unsigned* __restrict__ packed)
{
  int t = blockIdx.x * 256 + threadIdx.x;      // t in [0, 32*512)
  if (t >= NB * NW) return;
  int b = t >> 9, wcol = t & 511;
  float n = floorf(20.f + 41.f * rain_n_u[b]);
  float wf = (float)wcol;
  int cnt = 0;
  for (int s = 0; s < NS; ++s) {
    if ((float)s < n) {
      float xc = floorf(rain_u[(b * NS + s) * 3 + 0] * 512.f);
      if (wf >= xc - 1.f && wf <= xc) {
        float y0 = floorf(rain_u[(b * NS + s) * 3 + 1] * 256.f);
        float y1 = 256.f + floorf(rain_u[(b * NS + s) * 3 + 2] * 256.f);
        packed[t * NS + cnt] = (((unsigned)y0) << 16) | (unsigned)y1;
        ++cnt;
      }
    }
  }
  nlist[t] = cnt;
}

// ---- pointwise chain applied to an 8-row column strip ----
template<bool USE_LISTS>
__device__ __forceinline__ void chain_and_store(
    float acc[8], const PParams& P, int b, int gx, int gy0,
    const float* __restrict__ noise_plane, const float* __restrict__ rain_u,
    const int* __restrict__ nlist, const unsigned* __restrict__ packed,
    float* __restrict__ out_plane)
{
  const float fx = (float)gx;

  // 2. glare
  if (P.f1) {
    float dx = (fx - P.cx) * P.rxi;
    float dx2 = dx * dx;
    #pragma unroll
    for (int k = 0; k < 8; ++k) {
      float dy = ((float)(gy0 + k) - P.cy) * P.ryi;
      float g = __expf(-(dx2 + dy * dy));
      acc[k] = clip01(acc[k] + P.intensity * g);
    }
  }
  // 3. occlusion
  if (P.f2 && fx >= P.ox0 && fx < P.ox1) {
    #pragma unroll
    for (int k = 0; k < 8; ++k) {
      float fy = (float)(gy0 + k);
      if (fy >= P.oy0 && fy < P.oy1) acc[k] = 0.f;
    }
  }
  // 4. rain
  if (P.f3) {
    float cnt[8];
    #pragma unroll
    for (int k = 0; k < 8; ++k) cnt[k] = 0.f;
    if (USE_LISTS) {
      int base = b * NW + gx;
      int c = nlist[base];
      for (int j = 0; j < c; ++j) {
        unsigned p = packed[base * NS + j];
        float y0 = (float)(p >> 16), y1 = (float)(p & 0xffffu);
        #pragma unroll
        for (int k = 0; k < 8; ++k) {
          float fy = (float)(gy0 + k);
          cnt[k] += (fy >= y0 && fy < y1) ? 1.f : 0.f;
        }
      }
    } else {
      for (int s = 0; s < NS; ++s) {
        if ((float)s < P.nrain) {
          float xc = floorf(rain_u[(b * NS + s) * 3 + 0] * 512.f);
          if (fx >= xc - 1.f && fx <= xc) {
            float y0 = floorf(rain_u[(b * NS + s) * 3 + 1] * 256.f);
            float y1 = 256.f + floorf(rain_u[(b * NS + s) * 3 + 2] * 256.f);
            #pragma unroll
            for (int k = 0; k < 8; ++k) {
              float fy = (float)(gy0 + k);
              cnt[k] += (fy >= y0 && fy < y1) ? 1.f : 0.f;
            }
          }
        }
      }
    }
    #pragma unroll
    for (int k = 0; k < 8; ++k) {
      if (cnt[k] != 0.f) {
        float d = exp2f(cnt[k] * P.log1ma);
        acc[k] = clip01(acc[k] * d + (1.f - d));
      }
    }
  }
  // 5. salt & pepper (read noise only when gated on; noise is read-once ->
  // nontemporal to keep L2 for the reused blur rows)
  if (P.f4) {
    const float* np = noise_plane + (size_t)gy0 * NW + gx;
    #pragma unroll
    for (int k = 0; k < 8; ++k) {
      float nv = __builtin_nontemporal_load(np + (size_t)k * NW);
      acc[k] = (nv < P.thr_lo) ? 0.f : ((nv > P.thr_hi) ? 1.f : acc[k]);
    }
  }
  // output is write-once -> nontemporal store
  float* op = out_plane + (size_t)gy0 * NW + gx;
  #pragma unroll
  for (int k = 0; k < 8; ++k)
    __builtin_nontemporal_store(acc[k], op + (size_t)k * NW);
}

// r3 structure (one 64x64 tile per block, 22.5 KB LDS). Stage-1 interior
// body is branch-free (row clamp + zero mask) with constant trip count so
// the COMPILER can overlap next-iteration loads with current FMAs — no
// hand-pinned double buffers (r5 spilled: WRITE_SIZE 98->444 MB).
template<bool USE_LISTS>
__global__ __launch_bounds__(256, 4)
void fused_kernel(const float* __restrict__ x, const float* __restrict__ sigma_u,
                  const float* __restrict__ glare_u, const float* __restrict__ occ_u,
                  const float* __restrict__ rain_u, const float* __restrict__ rain_n_u,
                  const float* __restrict__ rain_alpha_u, const float* __restrict__ noise_u,
                  const float* __restrict__ noise_amt_u, const int* __restrict__ flags,
                  const int* __restrict__ nlist, const unsigned* __restrict__ packed,
                  float* __restrict__ out)
{
  const int b = blockIdx.z, ch = blockIdx.y;
  const int ty0 = (blockIdx.x >> 3) * TILE, tx0 = (blockIdx.x & 7) * TILE;
  const int tid = threadIdx.x;

  const int f0 = flags[b * 5 + 0] > 0;
  PParams P;
  P.f1 = flags[b * 5 + 1] > 0;
  P.f2 = flags[b * 5 + 2] > 0;
  P.f3 = flags[b * 5 + 3] > 0;
  P.f4 = flags[b * 5 + 4] > 0;
  {
    float g0 = glare_u[b * 5 + 0], g1 = glare_u[b * 5 + 1], g2 = glare_u[b * 5 + 2],
          g3 = glare_u[b * 5 + 3], g4 = glare_u[b * 5 + 4];
    P.intensity = 0.4f + 0.5f * g0;
    P.rxi = 1.f / ((0.1f + 0.25f * g1) * 256.f);   // W/2
    P.ryi = 1.f / ((0.1f + 0.25f * g2) * 256.f);   // H/2
    P.cx = (0.2f + 0.6f * g3) * 512.f;
    P.cy = (0.2f + 0.6f * g4) * 512.f;
    float o0 = occ_u[b * 4 + 0], o1 = occ_u[b * 4 + 1],
          o2 = occ_u[b * 4 + 2], o3 = occ_u[b * 4 + 3];
    float ph = floorf(512.f * (0.1f + 0.3f * o0));
    float pw = floorf(512.f * (0.1f + 0.3f * o1));
    P.oy0 = floorf(o2 * (512.f - ph)); P.oy1 = P.oy0 + ph;
    P.ox0 = floorf(o3 * (512.f - pw)); P.ox1 = P.ox0 + pw;
    P.log1ma = log2f(1.f - (0.15f + 0.35f * rain_alpha_u[b]));
    P.nrain = floorf(20.f + 41.f * rain_n_u[b]);
    float half_amt = 0.5f * (0.01f + 0.07f * noise_amt_u[b]);
    P.thr_lo = half_amt; P.thr_hi = 1.f - half_amt;
  }

  const size_t plane = ((size_t)(b * NC + ch)) * (size_t)(NH * NW);
  const float* xp = x + plane;
  const float* np = noise_u + plane;
  float* op = out + plane;

  __shared__ __align__(16) float s_hb[HALO * TILE];   // 22.5 KB

  if (f0) {
    // ---- blur weights in registers (__expf: 25 on the critical path) ----
    float sig = 1.f + 3.f * sigma_u[b];
    float ninv2s2 = -1.f / (2.f * sig * sig);
    float wr[KS]; float s = 0.f;
    #pragma unroll
    for (int t = 0; t < KS; ++t) {
      float d = (float)t - 12.f;
      wr[t] = __expf(d * d * ninv2s2);
      s += wr[t];
    }
    float inv = 1.f / s;
    #pragma unroll
    for (int t = 0; t < KS; ++t) wr[t] *= inv;

    // ---- stage 1: horizontal blur from global ----
    // thread = (row-group g in [0,16), col-quad q in [0,16)); rows g+16k.
    const int q = tid & 15, g = tid >> 4;
    const int gx0 = tx0 + q * 4;

    if (tx0 != 0 && tx0 != 448) {
      // ==== interior tile: branch-free body (clamp + mask), unroll 2 ====
      const float* cb = xp + (gx0 - HALF);
      #pragma unroll 2
      for (int k = 0; k < 6; ++k) {
        int r = g + 16 * k;              // 0..95; r<HALO is wave-uniform
        if (r < HALO) {
          int gy = ty0 + r - HALF;
          int cgy = min(max(gy, 0), NH - 1);              // safe clamped row
          float m = ((unsigned)gy < (unsigned)NH) ? 1.f : 0.f;  // zero-pad mask
          const float* p = cb + (size_t)cgy * NW;
          float win[28];
          #pragma unroll
          for (int j = 0; j < 7; ++j) {
            float4 v = *reinterpret_cast<const float4*>(p + 4 * j);
            win[4 * j + 0] = v.x; win[4 * j + 1] = v.y;
            win[4 * j + 2] = v.z; win[4 * j + 3] = v.w;
          }
          float a0 = 0.f, a1 = 0.f, a2 = 0.f, a3 = 0.f;
          #pragma unroll
          for (int t = 0; t < KS; ++t) {
            float wt = wr[t];
            a0 = fmaf(wt, win[t + 0], a0);
            a1 = fmaf(wt, win[t + 1], a1);
            a2 = fmaf(wt, win[t + 2], a2);
            a3 = fmaf(wt, win[t + 3], a3);
          }
          *reinterpret_cast<float4*>(&s_hb[r * TILE + q * 4]) =
              make_float4(a0 * m, a1 * m, a2 * m, a3 * m);
        }
      }
    } else {
      // ==== x-edge tile (tx0 == 0 or 448): guarded scalar loads ====
      for (int k = 0; k < 6; ++k) {
        int r = g + 16 * k;
        if (r < HALO) {
          int gy = ty0 + r - HALF;
          float a0 = 0.f, a1 = 0.f, a2 = 0.f, a3 = 0.f;
          if ((unsigned)gy < (unsigned)NH) {
            const float* rowp = xp + (size_t)gy * NW;
            float win[28];
            #pragma unroll
            for (int j = 0; j < 28; ++j) {
              int gx = gx0 - HALF + j;
              win[j] = ((unsigned)gx < (unsigned)NW) ? rowp[gx] : 0.f;
            }
            #pragma unroll
            for (int t = 0; t < KS; ++t) {
              float wt = wr[t];
              a0 = fmaf(wt, win[t + 0], a0);
              a1 = fmaf(wt, win[t + 1], a1);
              a2 = fmaf(wt, win[t + 2], a2);
              a3 = fmaf(wt, win[t + 3], a3);
            }
          }
          *reinterpret_cast<float4*>(&s_hb[r * TILE + q * 4]) =
              make_float4(a0, a1, a2, a3);
        }
      }
    }
    __syncthreads();

    // ---- stage 2: vertical blur on 8-row strips + fused pointwise chain ----
    for (int i = tid; i < 512; i += 256) {
      int xq = i & 63, sy = i >> 6;
      int gx = tx0 + xq, gy0 = ty0 + sy * 8;
      float wincol[32];
      #pragma unroll
      for (int j = 0; j < 32; ++j) wincol[j] = s_hb[(sy * 8 + j) * TILE + xq];
      float acc[8];
      #pragma unroll
      for (int k = 0; k < 8; ++k) {
        float a = 0.f;
        #pragma unroll
        for (int t = 0; t < KS; ++t) a = fmaf(wr[t], wincol[k + t], a);
        acc[k] = clip01(a);
      }
      chain_and_store<USE_LISTS>(acc, P, b, gx, gy0, np, rain_u, nlist, packed, op);
    }
  } else {
    // ---- no blur: pure streaming path (x read-once -> nontemporal) ----
    for (int i = tid; i < 512; i += 256) {
      int xq = i & 63, sy = i >> 6;
      int gx = tx0 + xq, gy0 = ty0 + sy * 8;
      float acc[8];
      #pragma unroll
      for (int k = 0; k < 8; ++k)
        acc[k] = __builtin_nontemporal_load(xp + (size_t)(gy0 + k) * NW + gx);
      chain_and_store<USE_LISTS>(acc, P, b, gx, gy0, np, rain_u, nlist, packed, op);
    }
  }
}

extern "C" void kernel_launch(void* const* d_in, const int* in_sizes, int n_in,
                              void* d_out, int out_size, void* d_ws, size_t ws_size,
                              hipStream_t stream)
{
  const float* x            = (const float*)d_in[0];
  const float* sigma_u      = (const float*)d_in[1];
  const float* glare_u      = (const float*)d_in[2];
  const float* occ_u        = (const float*)d_in[3];
  const float* rain_u       = (const float*)d_in[4];
  const float* rain_n_u     = (const float*)d_in[5];
  const float* rain_alpha_u = (const float*)d_in[6];
  const float* noise_u      = (const float*)d_in[7];
  const float* noise_amt_u  = (const float*)d_in[8];
  const int*   flags        = (const int*)d_in[9];
  float* out = (float*)d_out;

  const size_t nlist_bytes  = (size_t)NB * NW * sizeof(int);
  const size_t packed_bytes = (size_t)NB * NW * NS * sizeof(unsigned);
  const bool use_lists = ws_size >= nlist_bytes + packed_bytes;

  int* nlist = (int*)d_ws;
  unsigned* packed = (unsigned*)((char*)d_ws + nlist_bytes);

  dim3 grid(64, NC, NB);   // 8x8 tiles, 3 channels, 32 samples
  if (use_lists) {
    rain_cols_kernel<<<(NB * NW + 255) / 256, 256, 0, stream>>>(rain_u, rain_n_u, nlist, packed);
    fused_kernel<true><<<grid, 256, 0, stream>>>(
        x, sigma_u, glare_u, occ_u, rain_u, rain_n_u, rain_alpha_u,
        noise_u, noise_amt_u, flags, nlist, packed, out);
  } else {
    fused_kernel<false><<<grid, 256, 0, stream>>>(
        x, sigma_u, glare_u, occ_u, rain_u, rain_n_u, rain_alpha_u,
        noise_u, noise_amt_u, flags, (const int*)nullptr, (const unsigned*)nullptr, out);
  }
}

// Round 7
// 138.254 us; speedup vs baseline: 1.9050x; 1.1952x over previous
//
#include <hip/hip_runtime.h>

#define NB   32
#define NC   3
#define NH   512
#define NW   512
#define KS   25
#define HALF 12
#define TILE 64
#define HALO 88    // TILE + 2*HALF
#define NS   60
#define NTILES (64 * NC * NB)   // 6144
#define NBLOCKS 1792            // 7 blocks/CU — exactly the 22.5 KB LDS cap

__device__ __forceinline__ float clip01(float v) { return fminf(fmaxf(v, 0.f), 1.f); }

struct PParams {
  int f1, f2, f3, f4;
  float intensity, cx, cy, rxi, ryi;
  float oy0, oy1, ox0, ox1;
  float log1ma, nrain;
  float thr_lo, thr_hi;
};

// ---- rain column lists: each streak covers exactly 2 columns ----
__global__ void rain_cols_kernel(const float* __restrict__ rain_u,
                                 const float* __restrict__ rain_n_u,
                                 int* __restrict__ nlist,
                                 unsigned* __restrict__ packed)
{
  int t = blockIdx.x * 256 + threadIdx.x;      // t in [0, 32*512)
  if (t >= NB * NW) return;
  int b = t >> 9, wcol = t & 511;
  float n = floorf(20.f + 41.f * rain_n_u[b]);
  float wf = (float)wcol;
  int cnt = 0;
  for (int s = 0; s < NS; ++s) {
    if ((float)s < n) {
      float xc = floorf(rain_u[(b * NS + s) * 3 + 0] * 512.f);
      if (wf >= xc - 1.f && wf <= xc) {
        float y0 = floorf(rain_u[(b * NS + s) * 3 + 1] * 256.f);
        float y1 = 256.f + floorf(rain_u[(b * NS + s) * 3 + 2] * 256.f);
        packed[t * NS + cnt] = (((unsigned)y0) << 16) | (unsigned)y1;
        ++cnt;
      }
    }
  }
  nlist[t] = cnt;
}

// ---- pointwise chain applied to an 8-row column strip (r3 bodies, plain ld/st) ----
template<bool USE_LISTS>
__device__ __forceinline__ void chain_and_store(
    float acc[8], const PParams& P, int b, int gx, int gy0,
    const float* __restrict__ noise_plane, const float* __restrict__ rain_u,
    const int* __restrict__ nlist, const unsigned* __restrict__ packed,
    float* __restrict__ out_plane)
{
  const float fx = (float)gx;

  if (P.f1) {
    float dx = (fx - P.cx) * P.rxi;
    float dx2 = dx * dx;
    #pragma unroll
    for (int k = 0; k < 8; ++k) {
      float dy = ((float)(gy0 + k) - P.cy) * P.ryi;
      float g = __expf(-(dx2 + dy * dy));
      acc[k] = clip01(acc[k] + P.intensity * g);
    }
  }
  if (P.f2 && fx >= P.ox0 && fx < P.ox1) {
    #pragma unroll
    for (int k = 0; k < 8; ++k) {
      float fy = (float)(gy0 + k);
      if (fy >= P.oy0 && fy < P.oy1) acc[k] = 0.f;
    }
  }
  if (P.f3) {
    float cnt[8];
    #pragma unroll
    for (int k = 0; k < 8; ++k) cnt[k] = 0.f;
    if (USE_LISTS) {
      int base = b * NW + gx;
      int c = nlist[base];
      for (int j = 0; j < c; ++j) {
        unsigned p = packed[base * NS + j];
        float y0 = (float)(p >> 16), y1 = (float)(p & 0xffffu);
        #pragma unroll
        for (int k = 0; k < 8; ++k) {
          float fy = (float)(gy0 + k);
          cnt[k] += (fy >= y0 && fy < y1) ? 1.f : 0.f;
        }
      }
    } else {
      for (int s = 0; s < NS; ++s) {
        if ((float)s < P.nrain) {
          float xc = floorf(rain_u[(b * NS + s) * 3 + 0] * 512.f);
          if (fx >= xc - 1.f && fx <= xc) {
            float y0 = floorf(rain_u[(b * NS + s) * 3 + 1] * 256.f);
            float y1 = 256.f + floorf(rain_u[(b * NS + s) * 3 + 2] * 256.f);
            #pragma unroll
            for (int k = 0; k < 8; ++k) {
              float fy = (float)(gy0 + k);
              cnt[k] += (fy >= y0 && fy < y1) ? 1.f : 0.f;
            }
          }
        }
      }
    }
    #pragma unroll
    for (int k = 0; k < 8; ++k) {
      if (cnt[k] != 0.f) {
        float d = exp2f(cnt[k] * P.log1ma);
        acc[k] = clip01(acc[k] * d + (1.f - d));
      }
    }
  }
  if (P.f4) {
    const float* np = noise_plane + (size_t)gy0 * NW + gx;
    #pragma unroll
    for (int k = 0; k < 8; ++k) {
      float nv = np[(size_t)k * NW];
      acc[k] = (nv < P.thr_lo) ? 0.f : ((nv > P.thr_hi) ? 1.f : acc[k]);
    }
  }
  float* op = out_plane + (size_t)gy0 * NW + gx;
  #pragma unroll
  for (int k = 0; k < 8; ++k) op[(size_t)k * NW] = acc[k];
}

// ---- one 64x64 tile, r3 bodies verbatim ----
template<bool USE_LISTS>
__device__ __forceinline__ void process_tile(
    int t, int tid, float* __restrict__ s_hb,
    const float* __restrict__ x, const float* __restrict__ sigma_u,
    const float* __restrict__ glare_u, const float* __restrict__ occ_u,
    const float* __restrict__ rain_u, const float* __restrict__ rain_n_u,
    const float* __restrict__ rain_alpha_u, const float* __restrict__ noise_u,
    const float* __restrict__ noise_amt_u, const int* __restrict__ flags,
    const int* __restrict__ nlist, const unsigned* __restrict__ packed,
    float* __restrict__ out)
{
  const int tile = t & 63;
  const int pcb  = t >> 6;          // ch + 3*b
  const int b    = pcb / 3;
  const int ch   = pcb - 3 * b;
  const int ty0 = (tile >> 3) * TILE, tx0 = (tile & 7) * TILE;

  const int f0 = flags[b * 5 + 0] > 0;
  PParams P;
  P.f1 = flags[b * 5 + 1] > 0;
  P.f2 = flags[b * 5 + 2] > 0;
  P.f3 = flags[b * 5 + 3] > 0;
  P.f4 = flags[b * 5 + 4] > 0;
  {
    float g0 = glare_u[b * 5 + 0], g1 = glare_u[b * 5 + 1], g2 = glare_u[b * 5 + 2],
          g3 = glare_u[b * 5 + 3], g4 = glare_u[b * 5 + 4];
    P.intensity = 0.4f + 0.5f * g0;
    P.rxi = 1.f / ((0.1f + 0.25f * g1) * 256.f);   // W/2
    P.ryi = 1.f / ((0.1f + 0.25f * g2) * 256.f);   // H/2
    P.cx = (0.2f + 0.6f * g3) * 512.f;
    P.cy = (0.2f + 0.6f * g4) * 512.f;
    float o0 = occ_u[b * 4 + 0], o1 = occ_u[b * 4 + 1],
          o2 = occ_u[b * 4 + 2], o3 = occ_u[b * 4 + 3];
    float ph = floorf(512.f * (0.1f + 0.3f * o0));
    float pw = floorf(512.f * (0.1f + 0.3f * o1));
    P.oy0 = floorf(o2 * (512.f - ph)); P.oy1 = P.oy0 + ph;
    P.ox0 = floorf(o3 * (512.f - pw)); P.ox1 = P.ox0 + pw;
    P.log1ma = log2f(1.f - (0.15f + 0.35f * rain_alpha_u[b]));
    P.nrain = floorf(20.f + 41.f * rain_n_u[b]);
    float half_amt = 0.5f * (0.01f + 0.07f * noise_amt_u[b]);
    P.thr_lo = half_amt; P.thr_hi = 1.f - half_amt;
  }

  const size_t plane = ((size_t)(b * NC + ch)) * (size_t)(NH * NW);
  const float* xp = x + plane;
  const float* np = noise_u + plane;
  float* op = out + plane;

  if (f0) {
    float sig = 1.f + 3.f * sigma_u[b];
    float ninv2s2 = -1.f / (2.f * sig * sig);
    float wr[KS]; float s = 0.f;
    #pragma unroll
    for (int tt = 0; tt < KS; ++tt) {
      float d = (float)tt - 12.f;
      wr[tt] = __expf(d * d * ninv2s2);
      s += wr[tt];
    }
    float inv = 1.f / s;
    #pragma unroll
    for (int tt = 0; tt < KS; ++tt) wr[tt] *= inv;

    // ---- stage 1: horizontal blur straight from global (r3 body) ----
    for (int i = tid; i < HALO * 16; i += 256) {
      int r = i >> 4, q = i & 15;
      int gy = ty0 + r - HALF;
      float a0 = 0.f, a1 = 0.f, a2 = 0.f, a3 = 0.f;
      if ((unsigned)gy < (unsigned)NH) {
        const float* rowp = xp + (size_t)gy * NW;
        int gx0 = tx0 + q * 4;
        float win[28];
        if (gx0 - HALF >= 0 && gx0 + 15 < NW) {   // interior: 7 aligned float4
          #pragma unroll
          for (int j = 0; j < 7; ++j) {
            float4 v = *reinterpret_cast<const float4*>(rowp + gx0 - HALF + 4 * j);
            win[4 * j + 0] = v.x; win[4 * j + 1] = v.y;
            win[4 * j + 2] = v.z; win[4 * j + 3] = v.w;
          }
        } else {                                  // x-edge: guarded scalar loads
          #pragma unroll
          for (int j = 0; j < 28; ++j) {
            int gx = gx0 - HALF + j;
            win[j] = ((unsigned)gx < (unsigned)NW) ? rowp[gx] : 0.f;
          }
        }
        #pragma unroll
        for (int tt = 0; tt < KS; ++tt) {
          float wt = wr[tt];
          a0 = fmaf(wt, win[tt + 0], a0);
          a1 = fmaf(wt, win[tt + 1], a1);
          a2 = fmaf(wt, win[tt + 2], a2);
          a3 = fmaf(wt, win[tt + 3], a3);
        }
      }
      *reinterpret_cast<float4*>(&s_hb[r * TILE + (i & 15) * 4]) =
          make_float4(a0, a1, a2, a3);
    }
    __syncthreads();

    // ---- stage 2: vertical blur + fused chain (r3 body) ----
    for (int i = tid; i < 512; i += 256) {
      int xq = i & 63, sy = i >> 6;
      int gx = tx0 + xq, gy0 = ty0 + sy * 8;
      float wincol[32];
      #pragma unroll
      for (int j = 0; j < 32; ++j) wincol[j] = s_hb[(sy * 8 + j) * TILE + xq];
      float acc[8];
      #pragma unroll
      for (int k = 0; k < 8; ++k) {
        float a = 0.f;
        #pragma unroll
        for (int tt = 0; tt < KS; ++tt) a = fmaf(wr[tt], wincol[k + tt], a);
        acc[k] = clip01(a);
      }
      chain_and_store<USE_LISTS>(acc, P, b, gx, gy0, np, rain_u, nlist, packed, op);
    }
  } else {
    for (int i = tid; i < 512; i += 256) {
      int xq = i & 63, sy = i >> 6;
      int gx = tx0 + xq, gy0 = ty0 + sy * 8;
      float acc[8];
      #pragma unroll
      for (int k = 0; k < 8; ++k) acc[k] = xp[(size_t)(gy0 + k) * NW + gx];
      chain_and_store<USE_LISTS>(acc, P, b, gx, gy0, np, rain_u, nlist, packed, op);
    }
  }
}

// Work-stealing: blocks stay resident until the tile queue drains, so the
// 4x cost spread between blur and non-blur tiles can't strand CU slots
// (r4's static 3-tiles/block showed 28% occupancy: early-finishing blocks
// exited and their slots sat empty while all-blur stragglers set the tail).
template<bool USE_LISTS>
__global__ __launch_bounds__(256, 4)
void fused_steal_kernel(const float* __restrict__ x, const float* __restrict__ sigma_u,
                        const float* __restrict__ glare_u, const float* __restrict__ occ_u,
                        const float* __restrict__ rain_u, const float* __restrict__ rain_n_u,
                        const float* __restrict__ rain_alpha_u, const float* __restrict__ noise_u,
                        const float* __restrict__ noise_amt_u, const int* __restrict__ flags,
                        const int* __restrict__ nlist, const unsigned* __restrict__ packed,
                        int* __restrict__ counter, float* __restrict__ out)
{
  const int tid = threadIdx.x;
  __shared__ __align__(16) float s_hb[HALO * TILE];   // 22.5 KB
  __shared__ int s_t;

  for (;;) {
    if (tid == 0) s_t = atomicAdd(counter, 1);
    __syncthreads();                 // broadcast t; also WAR barrier for s_hb
    int t = s_t;
    if (t >= NTILES) break;          // uniform exit
    process_tile<USE_LISTS>(t, tid, s_hb, x, sigma_u, glare_u, occ_u, rain_u,
                            rain_n_u, rain_alpha_u, noise_u, noise_amt_u,
                            flags, nlist, packed, out);
    __syncthreads();                 // s_t / s_hb safe to overwrite next iter
  }
}

// Fallback when d_ws is too small for the counter: r3's plain grid.
template<bool USE_LISTS>
__global__ __launch_bounds__(256, 4)
void fused_plain_kernel(const float* __restrict__ x, const float* __restrict__ sigma_u,
                        const float* __restrict__ glare_u, const float* __restrict__ occ_u,
                        const float* __restrict__ rain_u, const float* __restrict__ rain_n_u,
                        const float* __restrict__ rain_alpha_u, const float* __restrict__ noise_u,
                        const float* __restrict__ noise_amt_u, const int* __restrict__ flags,
                        const int* __restrict__ nlist, const unsigned* __restrict__ packed,
                        float* __restrict__ out)
{
  __shared__ __align__(16) float s_hb[HALO * TILE];
  int t = ((blockIdx.z * NC + blockIdx.y) << 6) | blockIdx.x;
  process_tile<USE_LISTS>(t, threadIdx.x, s_hb, x, sigma_u, glare_u, occ_u,
                          rain_u, rain_n_u, rain_alpha_u, noise_u, noise_amt_u,
                          flags, nlist, packed, out);
}

extern "C" void kernel_launch(void* const* d_in, const int* in_sizes, int n_in,
                              void* d_out, int out_size, void* d_ws, size_t ws_size,
                              hipStream_t stream)
{
  const float* x            = (const float*)d_in[0];
  const float* sigma_u      = (const float*)d_in[1];
  const float* glare_u      = (const float*)d_in[2];
  const float* occ_u        = (const float*)d_in[3];
  const float* rain_u       = (const float*)d_in[4];
  const float* rain_n_u     = (const float*)d_in[5];
  const float* rain_alpha_u = (const float*)d_in[6];
  const float* noise_u      = (const float*)d_in[7];
  const float* noise_amt_u  = (const float*)d_in[8];
  const int*   flags        = (const int*)d_in[9];
  float* out = (float*)d_out;

  // ws layout: [0,128): steal counter | [128, +nlist): nlist | then packed
  const size_t nlist_bytes  = (size_t)NB * NW * sizeof(int);
  const size_t packed_bytes = (size_t)NB * NW * NS * sizeof(unsigned);
  const bool can_steal = ws_size >= 128;
  const bool use_lists = ws_size >= 128 + nlist_bytes + packed_bytes;

  int* counter = (int*)d_ws;
  int* nlist = (int*)((char*)d_ws + 128);
  unsigned* packed = (unsigned*)((char*)d_ws + 128 + nlist_bytes);

  if (can_steal) hipMemsetAsync(counter, 0, sizeof(int), stream);
  if (use_lists)
    rain_cols_kernel<<<(NB * NW + 255) / 256, 256, 0, stream>>>(rain_u, rain_n_u, nlist, packed);

  if (can_steal) {
    if (use_lists)
      fused_steal_kernel<true><<<NBLOCKS, 256, 0, stream>>>(
          x, sigma_u, glare_u, occ_u, rain_u, rain_n_u, rain_alpha_u,
          noise_u, noise_amt_u, flags, nlist, packed, counter, out);
    else
      fused_steal_kernel<false><<<NBLOCKS, 256, 0, stream>>>(
          x, sigma_u, glare_u, occ_u, rain_u, rain_n_u, rain_alpha_u,
          noise_u, noise_amt_u, flags, nullptr, nullptr, counter, out);
  } else {
    dim3 grid(64, NC, NB);
    fused_plain_kernel<false><<<grid, 256, 0, stream>>>(
        x, sigma_u, glare_u, occ_u, rain_u, rain_n_u, rain_alpha_u,
        noise_u, noise_amt_u, flags, nullptr, nullptr, out);
  }
}

// Round 8
// 136.756 us; speedup vs baseline: 1.9259x; 1.0110x over previous
//
#include <hip/hip_runtime.h>

#define NB   32
#define NC   3
#define NH   512
#define NW   512
#define KS   25
#define HALF 12
#define NS   60
#define PLN  (NH * NW)        // 262144
#define NPL  (NB * NC)        // 96

// ---- workspace layout ----
#define HB_BYTES  ((size_t)NPL * PLN * 4)             // 100,663,296
#define WTS_OFF   HB_BYTES
#define WTS_BYTES ((size_t)4096)                      // 32 x 28 floats, padded
#define NL_OFF    (WTS_OFF + WTS_BYTES)
#define NL_BYTES  ((size_t)NB * NW * 4)
#define PK_OFF    (NL_OFF + NL_BYTES)
#define PK_BYTES  ((size_t)NB * NW * NS * 4)
#define WS_NEED   (PK_OFF + PK_BYTES)                 // ~104.7 MB

__device__ __forceinline__ float clip01(float v) { return fminf(fmaxf(v, 0.f), 1.f); }

struct PParams {
  int f1, f2, f3, f4;
  float intensity, cx, cy, rxi, ryi;
  float oy0, oy1, ox0, ox1;
  float log1ma;
  float thr_lo, thr_hi;
};

__device__ __forceinline__ PParams load_params(
    int b, const int* __restrict__ flags, const float* __restrict__ glare_u,
    const float* __restrict__ occ_u, const float* __restrict__ rain_alpha_u,
    const float* __restrict__ noise_amt_u)
{
  PParams P;
  P.f1 = flags[b * 5 + 1] > 0;
  P.f2 = flags[b * 5 + 2] > 0;
  P.f3 = flags[b * 5 + 3] > 0;
  P.f4 = flags[b * 5 + 4] > 0;
  float g0 = glare_u[b * 5 + 0], g1 = glare_u[b * 5 + 1], g2 = glare_u[b * 5 + 2],
        g3 = glare_u[b * 5 + 3], g4 = glare_u[b * 5 + 4];
  P.intensity = 0.4f + 0.5f * g0;
  P.rxi = 1.f / ((0.1f + 0.25f * g1) * 256.f);
  P.ryi = 1.f / ((0.1f + 0.25f * g2) * 256.f);
  P.cx = (0.2f + 0.6f * g3) * 512.f;
  P.cy = (0.2f + 0.6f * g4) * 512.f;
  float o0 = occ_u[b * 4 + 0], o1 = occ_u[b * 4 + 1],
        o2 = occ_u[b * 4 + 2], o3 = occ_u[b * 4 + 3];
  float ph = floorf(512.f * (0.1f + 0.3f * o0));
  float pw = floorf(512.f * (0.1f + 0.3f * o1));
  P.oy0 = floorf(o2 * (512.f - ph)); P.oy1 = P.oy0 + ph;
  P.ox0 = floorf(o3 * (512.f - pw)); P.ox1 = P.ox0 + pw;
  P.log1ma = log2f(1.f - (0.15f + 0.35f * rain_alpha_u[b]));
  float half_amt = 0.5f * (0.01f + 0.07f * noise_amt_u[b]);
  P.thr_lo = half_amt; P.thr_hi = 1.f - half_amt;
  return P;
}

// ---- prep: rain column lists (blocks 0..63) + per-sample blur weights (block 64) ----
__global__ void prep_kernel(const float* __restrict__ rain_u,
                            const float* __restrict__ rain_n_u,
                            const float* __restrict__ sigma_u,
                            int* __restrict__ nlist,
                            unsigned* __restrict__ packed,
                            float* __restrict__ wts)
{
  if (blockIdx.x == 64) {
    int b = threadIdx.x;
    if (b < NB) {
      float sig = 1.f + 3.f * sigma_u[b];
      float ninv = -1.f / (2.f * sig * sig);
      float w[KS]; float s = 0.f;
      #pragma unroll
      for (int j = 0; j < KS; ++j) {
        float d = (float)j - 12.f;
        w[j] = __expf(d * d * ninv);
        s += w[j];
      }
      float inv = 1.f / s;
      #pragma unroll
      for (int j = 0; j < KS; ++j) wts[b * 28 + j] = w[j] * inv;
    }
    return;
  }
  int t = blockIdx.x * 256 + threadIdx.x;      // [0, 32*512)
  if (t >= NB * NW) return;
  int b = t >> 9, wcol = t & 511;
  float n = floorf(20.f + 41.f * rain_n_u[b]);
  float wf = (float)wcol;
  int cnt = 0;
  for (int s = 0; s < NS; ++s) {
    if ((float)s < n) {
      float xc = floorf(rain_u[(b * NS + s) * 3 + 0] * 512.f);
      if (wf >= xc - 1.f && wf <= xc) {
        float y0 = floorf(rain_u[(b * NS + s) * 3 + 1] * 256.f);
        float y1 = 256.f + floorf(rain_u[(b * NS + s) * 3 + 2] * 256.f);
        packed[t * NS + cnt] = (((unsigned)y0) << 16) | (unsigned)y1;
        ++cnt;
      }
    }
  }
  nlist[t] = cnt;
}

// ---- K1: H-blur row streamer (blur samples only). No LDS, no barriers. ----
__global__ __launch_bounds__(256, 4)
void hblur_kernel(const float* __restrict__ x, const int* __restrict__ flags,
                  const float* __restrict__ wts, float* __restrict__ hb)
{
  const int b = blockIdx.z;
  if (flags[b * 5] <= 0) return;               // non-blur sample: nothing to do
  const int ch = blockIdx.y;
  const int tid = threadIdx.x;
  const int row = (blockIdx.x << 1) | (tid >> 7);   // 2 rows per block
  const int q = tid & 127, gx0 = q << 2;

  float w[KS];
  const float* wp = wts + b * 28;              // sample-uniform -> scalar loads
  #pragma unroll
  for (int j = 0; j < KS; ++j) w[j] = wp[j];

  const size_t plane = (size_t)(b * NC + ch) * PLN;
  const float* rowp = x + plane + (size_t)row * NW;

  float win[28];
  if (q >= 3 && q <= 124) {                    // interior: 7 aligned float4
    #pragma unroll
    for (int j = 0; j < 7; ++j) {
      float4 v = *reinterpret_cast<const float4*>(rowp + gx0 - HALF + 4 * j);
      win[4 * j + 0] = v.x; win[4 * j + 1] = v.y;
      win[4 * j + 2] = v.z; win[4 * j + 3] = v.w;
    }
  } else {                                     // row-edge: guarded scalars
    #pragma unroll
    for (int j = 0; j < 28; ++j) {
      int gx = gx0 - HALF + j;
      win[j] = ((unsigned)gx < (unsigned)NW) ? rowp[gx] : 0.f;
    }
  }
  float a0 = 0.f, a1 = 0.f, a2 = 0.f, a3 = 0.f;
  #pragma unroll
  for (int t = 0; t < KS; ++t) {
    float wt = w[t];
    a0 = fmaf(wt, win[t + 0], a0);
    a1 = fmaf(wt, win[t + 1], a1);
    a2 = fmaf(wt, win[t + 2], a2);
    a3 = fmaf(wt, win[t + 3], a3);
  }
  *reinterpret_cast<float4*>(hb + plane + (size_t)row * NW + gx0) =
      make_float4(a0, a1, a2, a3);
}

// ---- chain on a 4-col x 8-row quad block (all static indexing) ----
__device__ __forceinline__ void chain_quad(
    float a[8][4], const PParams& P, int b, int gx0, int gy0,
    const float* __restrict__ np_plane, const int* __restrict__ nlist,
    const unsigned* __restrict__ packed, float* __restrict__ op_plane)
{
  if (P.f1) {
    float dx2[4];
    #pragma unroll
    for (int c = 0; c < 4; ++c) {
      float dx = ((float)(gx0 + c) - P.cx) * P.rxi;
      dx2[c] = dx * dx;
    }
    #pragma unroll
    for (int k = 0; k < 8; ++k) {
      float dy = ((float)(gy0 + k) - P.cy) * P.ryi;
      float dy2 = dy * dy;
      #pragma unroll
      for (int c = 0; c < 4; ++c) {
        float g = __expf(-(dx2[c] + dy2));
        a[k][c] = clip01(a[k][c] + P.intensity * g);
      }
    }
  }
  if (P.f2) {
    #pragma unroll
    for (int c = 0; c < 4; ++c) {
      float fx = (float)(gx0 + c);
      if (fx >= P.ox0 && fx < P.ox1) {
        #pragma unroll
        for (int k = 0; k < 8; ++k) {
          float fy = (float)(gy0 + k);
          if (fy >= P.oy0 && fy < P.oy1) a[k][c] = 0.f;
        }
      }
    }
  }
  if (P.f3) {
    #pragma unroll
    for (int c = 0; c < 4; ++c) {
      int base = b * NW + gx0 + c;
      int n = nlist[base];
      if (n > 0) {
        float cnt[8];
        #pragma unroll
        for (int k = 0; k < 8; ++k) cnt[k] = 0.f;
        for (int j = 0; j < n; ++j) {
          unsigned p = packed[base * NS + j];
          float y0 = (float)(p >> 16), y1 = (float)(p & 0xffffu);
          #pragma unroll
          for (int k = 0; k < 8; ++k) {
            float fy = (float)(gy0 + k);
            cnt[k] += (fy >= y0 && fy < y1) ? 1.f : 0.f;
          }
        }
        #pragma unroll
        for (int k = 0; k < 8; ++k) {
          if (cnt[k] != 0.f) {
            float d = exp2f(cnt[k] * P.log1ma);
            a[k][c] = clip01(a[k][c] * d + (1.f - d));
          }
        }
      }
    }
  }
  if (P.f4) {
    #pragma unroll
    for (int k = 0; k < 8; ++k) {
      float4 nv = *reinterpret_cast<const float4*>(
          np_plane + (size_t)(gy0 + k) * NW + gx0);
      a[k][0] = (nv.x < P.thr_lo) ? 0.f : ((nv.x > P.thr_hi) ? 1.f : a[k][0]);
      a[k][1] = (nv.y < P.thr_lo) ? 0.f : ((nv.y > P.thr_hi) ? 1.f : a[k][1]);
      a[k][2] = (nv.z < P.thr_lo) ? 0.f : ((nv.z > P.thr_hi) ? 1.f : a[k][2]);
      a[k][3] = (nv.w < P.thr_lo) ? 0.f : ((nv.w > P.thr_hi) ? 1.f : a[k][3]);
    }
  }
  #pragma unroll
  for (int k = 0; k < 8; ++k)
    *reinterpret_cast<float4*>(op_plane + (size_t)(gy0 + k) * NW + gx0) =
        make_float4(a[k][0], a[k][1], a[k][2], a[k][3]);
}

// ---- K2: V-blur + chain streamer (all samples). No LDS, no barriers. ----
// XCD-chunked bijection keeps adjacent y-strips (which share halo rows) on
// the same XCD's L2. 3072 blocks = 8 XCDs x 384.
__global__ __launch_bounds__(256, 4)
void vchain_kernel(const float* __restrict__ x, const float* __restrict__ hb,
                   const float* __restrict__ wts,
                   const float* __restrict__ glare_u, const float* __restrict__ occ_u,
                   const float* __restrict__ rain_alpha_u,
                   const float* __restrict__ noise_u, const float* __restrict__ noise_amt_u,
                   const int* __restrict__ flags,
                   const int* __restrict__ nlist, const unsigned* __restrict__ packed,
                   float* __restrict__ out)
{
  const int lb = blockIdx.x;
  const int t = (lb & 7) * 384 + (lb >> 3);   // bijective XCD-chunk swizzle
  const int strip = t & 31;                   // 16-row strip within plane
  const int pl = t >> 5;                      // plane 0..95
  const int b = pl / 3;
  const int tid = threadIdx.x;
  const int gy0 = strip * 16 + ((tid >> 7) << 3);
  const int gx0 = (tid & 127) << 2;

  const int f0 = flags[b * 5] > 0;
  PParams P = load_params(b, flags, glare_u, occ_u, rain_alpha_u, noise_amt_u);
  const size_t plane = (size_t)pl * PLN;

  float a[8][4];
  if (f0) {
    float w[KS];
    const float* wp = wts + b * 28;
    #pragma unroll
    for (int j = 0; j < KS; ++j) w[j] = wp[j];
    #pragma unroll
    for (int k = 0; k < 8; ++k) {
      a[k][0] = 0.f; a[k][1] = 0.f; a[k][2] = 0.f; a[k][3] = 0.f;
    }
    const float* hp = hb + plane + gx0;
    #pragma unroll
    for (int m = 0; m < 32; ++m) {            // input row gy0-12+m
      int gy = gy0 - 12 + m;
      if ((unsigned)gy < (unsigned)NH) {      // wave-uniform (zero-pad skip)
        float4 v = *reinterpret_cast<const float4*>(hp + (size_t)gy * NW);
        #pragma unroll
        for (int k = 0; k < 8; ++k) {
          constexpr int dummy = 0; (void)dummy;
          int wi = m - k;                     // compile-time after unroll
          if (wi >= 0 && wi <= 24) {
            float wt = w[wi];
            a[k][0] = fmaf(wt, v.x, a[k][0]);
            a[k][1] = fmaf(wt, v.y, a[k][1]);
            a[k][2] = fmaf(wt, v.z, a[k][2]);
            a[k][3] = fmaf(wt, v.w, a[k][3]);
          }
        }
      }
    }
    #pragma unroll
    for (int k = 0; k < 8; ++k) {
      a[k][0] = clip01(a[k][0]); a[k][1] = clip01(a[k][1]);
      a[k][2] = clip01(a[k][2]); a[k][3] = clip01(a[k][3]);
    }
  } else {
    const float* xp = x + plane + gx0;
    #pragma unroll
    for (int k = 0; k < 8; ++k) {
      float4 v = *reinterpret_cast<const float4*>(xp + (size_t)(gy0 + k) * NW);
      a[k][0] = v.x; a[k][1] = v.y; a[k][2] = v.z; a[k][3] = v.w;
    }
  }
  chain_quad(a, P, b, gx0, gy0, noise_u + plane, nlist, packed, out + plane);
}

// ---- fallback (ws too small): r3's fused single kernel, no lists ----
__global__ __launch_bounds__(256, 4)
void fallback_kernel(const float* __restrict__ x, const float* __restrict__ sigma_u,
                     const float* __restrict__ glare_u, const float* __restrict__ occ_u,
                     const float* __restrict__ rain_u, const float* __restrict__ rain_n_u,
                     const float* __restrict__ rain_alpha_u, const float* __restrict__ noise_u,
                     const float* __restrict__ noise_amt_u, const int* __restrict__ flags,
                     float* __restrict__ out)
{
  const int b = blockIdx.z, ch = blockIdx.y;
  const int ty0 = (blockIdx.x >> 3) * 64, tx0 = (blockIdx.x & 7) * 64;
  const int tid = threadIdx.x;
  const int f0 = flags[b * 5] > 0;
  PParams P = load_params(b, flags, glare_u, occ_u, rain_alpha_u, noise_amt_u);
  const float nrain = floorf(20.f + 41.f * rain_n_u[b]);
  const size_t plane = (size_t)(b * NC + ch) * PLN;
  const float* xp = x + plane;
  const float* np = noise_u + plane;
  float* op = out + plane;

  __shared__ __align__(16) float s_hb[88 * 64];

  float wr[KS];
  if (f0) {
    float sig = 1.f + 3.f * sigma_u[b];
    float ninv = -1.f / (2.f * sig * sig);
    float s = 0.f;
    #pragma unroll
    for (int t = 0; t < KS; ++t) {
      float d = (float)t - 12.f;
      wr[t] = __expf(d * d * ninv); s += wr[t];
    }
    float inv = 1.f / s;
    #pragma unroll
    for (int t = 0; t < KS; ++t) wr[t] *= inv;

    for (int i = tid; i < 88 * 16; i += 256) {
      int r = i >> 4, q = i & 15;
      int gy = ty0 + r - HALF;
      float a0 = 0.f, a1 = 0.f, a2 = 0.f, a3 = 0.f;
      if ((unsigned)gy < (unsigned)NH) {
        const float* rowp = xp + (size_t)gy * NW;
        int gx0 = tx0 + q * 4;
        float win[28];
        if (gx0 - HALF >= 0 && gx0 + 15 < NW) {
          #pragma unroll
          for (int j = 0; j < 7; ++j) {
            float4 v = *reinterpret_cast<const float4*>(rowp + gx0 - HALF + 4 * j);
            win[4 * j + 0] = v.x; win[4 * j + 1] = v.y;
            win[4 * j + 2] = v.z; win[4 * j + 3] = v.w;
          }
        } else {
          #pragma unroll
          for (int j = 0; j < 28; ++j) {
            int gx = gx0 - HALF + j;
            win[j] = ((unsigned)gx < (unsigned)NW) ? rowp[gx] : 0.f;
          }
        }
        #pragma unroll
        for (int t = 0; t < KS; ++t) {
          float wt = wr[t];
          a0 = fmaf(wt, win[t + 0], a0);
          a1 = fmaf(wt, win[t + 1], a1);
          a2 = fmaf(wt, win[t + 2], a2);
          a3 = fmaf(wt, win[t + 3], a3);
        }
      }
      *reinterpret_cast<float4*>(&s_hb[r * 64 + (i & 15) * 4]) =
          make_float4(a0, a1, a2, a3);
    }
    __syncthreads();
  }

  for (int i = tid; i < 512; i += 256) {
    int xq = i & 63, sy = i >> 6;
    int gx = tx0 + xq, gy0 = ty0 + sy * 8;
    float acc[8];
    if (f0) {
      float wincol[32];
      #pragma unroll
      for (int j = 0; j < 32; ++j) wincol[j] = s_hb[(sy * 8 + j) * 64 + xq];
      #pragma unroll
      for (int k = 0; k < 8; ++k) {
        float a = 0.f;
        #pragma unroll
        for (int t = 0; t < KS; ++t) a = fmaf(wr[t], wincol[k + t], a);
        acc[k] = clip01(a);
      }
    } else {
      #pragma unroll
      for (int k = 0; k < 8; ++k) acc[k] = xp[(size_t)(gy0 + k) * NW + gx];
    }
    const float fx = (float)gx;
    if (P.f1) {
      float dx = (fx - P.cx) * P.rxi;
      float dx2 = dx * dx;
      #pragma unroll
      for (int k = 0; k < 8; ++k) {
        float dy = ((float)(gy0 + k) - P.cy) * P.ryi;
        acc[k] = clip01(acc[k] + P.intensity * __expf(-(dx2 + dy * dy)));
      }
    }
    if (P.f2 && fx >= P.ox0 && fx < P.ox1) {
      #pragma unroll
      for (int k = 0; k < 8; ++k) {
        float fy = (float)(gy0 + k);
        if (fy >= P.oy0 && fy < P.oy1) acc[k] = 0.f;
      }
    }
    if (P.f3) {
      float cnt[8];
      #pragma unroll
      for (int k = 0; k < 8; ++k) cnt[k] = 0.f;
      for (int s = 0; s < NS; ++s) {
        if ((float)s < nrain) {
          float xc = floorf(rain_u[(b * NS + s) * 3 + 0] * 512.f);
          if (fx >= xc - 1.f && fx <= xc) {
            float y0 = floorf(rain_u[(b * NS + s) * 3 + 1] * 256.f);
            float y1 = 256.f + floorf(rain_u[(b * NS + s) * 3 + 2] * 256.f);
            #pragma unroll
            for (int k = 0; k < 8; ++k) {
              float fy = (float)(gy0 + k);
              cnt[k] += (fy >= y0 && fy < y1) ? 1.f : 0.f;
            }
          }
        }
      }
      #pragma unroll
      for (int k = 0; k < 8; ++k) {
        if (cnt[k] != 0.f) {
          float d = exp2f(cnt[k] * P.log1ma);
          acc[k] = clip01(acc[k] * d + (1.f - d));
        }
      }
    }
    if (P.f4) {
      #pragma unroll
      for (int k = 0; k < 8; ++k) {
        float nv = np[(size_t)(gy0 + k) * NW + gx];
        acc[k] = (nv < P.thr_lo) ? 0.f : ((nv > P.thr_hi) ? 1.f : acc[k]);
      }
    }
    #pragma unroll
    for (int k = 0; k < 8; ++k) op[(size_t)(gy0 + k) * NW + gx] = acc[k];
  }
}

extern "C" void kernel_launch(void* const* d_in, const int* in_sizes, int n_in,
                              void* d_out, int out_size, void* d_ws, size_t ws_size,
                              hipStream_t stream)
{
  const float* x            = (const float*)d_in[0];
  const float* sigma_u      = (const float*)d_in[1];
  const float* glare_u      = (const float*)d_in[2];
  const float* occ_u        = (const float*)d_in[3];
  const float* rain_u       = (const float*)d_in[4];
  const float* rain_n_u     = (const float*)d_in[5];
  const float* rain_alpha_u = (const float*)d_in[6];
  const float* noise_u      = (const float*)d_in[7];
  const float* noise_amt_u  = (const float*)d_in[8];
  const int*   flags        = (const int*)d_in[9];
  float* out = (float*)d_out;

  if (ws_size >= WS_NEED) {
    float*    hb     = (float*)d_ws;
    float*    wts    = (float*)((char*)d_ws + WTS_OFF);
    int*      nlist  = (int*)((char*)d_ws + NL_OFF);
    unsigned* packed = (unsigned*)((char*)d_ws + PK_OFF);

    prep_kernel<<<65, 256, 0, stream>>>(rain_u, rain_n_u, sigma_u, nlist, packed, wts);
    hblur_kernel<<<dim3(NH / 2, NC, NB), 256, 0, stream>>>(x, flags, wts, hb);
    vchain_kernel<<<3072, 256, 0, stream>>>(
        x, hb, wts, glare_u, occ_u, rain_alpha_u, noise_u, noise_amt_u,
        flags, nlist, packed, out);
  } else {
    dim3 grid(64, NC, NB);
    fallback_kernel<<<grid, 256, 0, stream>>>(
        x, sigma_u, glare_u, occ_u, rain_u, rain_n_u, rain_alpha_u,
        noise_u, noise_amt_u, flags, out);
  }
}